// Round 3
// baseline (139.625 us; speedup 1.0000x reference)
//
#include <hip/hip_runtime.h>
#include <hip/hip_fp16.h>

typedef _Float16 f16x8 __attribute__((ext_vector_type(8)));
typedef float f32x4 __attribute__((ext_vector_type(4)));

#define FEAT 44
#define TED  84
#define ESTR 88      // embedh row stride in halves (176 B)
#define MT   128     // nodes per block
#define WN   32      // nodes per wave
#define ISTD_OFF 32768

// ---------------- kernel 1: per-graph embed + inv_std; last block repacks weights ----------------
__global__ void embed_prep(const float* __restrict__ t_arr, const float* __restrict__ W_f,
                           const float* __restrict__ embed_w, const float* __restrict__ embed_b,
                           const float* __restrict__ w0, const float* __restrict__ w1,
                           const float* __restrict__ w2,
                           _Float16* __restrict__ embedh, float* __restrict__ inv_std,
                           _Float16* __restrict__ w0h, _Float16* __restrict__ w1h,
                           _Float16* __restrict__ w2h, int B) {
    int g   = blockIdx.x;
    int tid = threadIdx.x;
    if (g == B) {   // weight repack block
        for (int i = tid; i < 64 * 128; i += 128) w0h[i] = (_Float16)w0[i];
        for (int i = tid; i < 32 * 64;  i += 128) w1h[i] = (_Float16)w1[i];
        for (int i = tid; i < 16 * 32;  i += 128) w2h[i] = (i < 4 * 32) ? (_Float16)w2[i] : (_Float16)0.f;
        return;
    }
    __shared__ float temb[TED];
    float tv = t_arr[g];
    if (tid < TED) {
        int j   = (tid < TED / 2) ? tid : tid - TED / 2;
        float x = tv * W_f[j] * 6.283185307179586f;
        temb[tid] = (tid < TED / 2) ? sinf(x) : cosf(x);
    }
    __syncthreads();
    if (tid < TED) {
        const float* wr = embed_w + tid * TED;
        float s = embed_b[tid];
        #pragma unroll 4
        for (int j = 0; j < TED; ++j) s = fmaf(temb[j], wr[j], s);
        float sw = s / (1.0f + __expf(-s));
        embedh[(size_t)g * ESTR + tid] = (_Float16)sw;
    } else if (tid < ESTR) {
        embedh[(size_t)g * ESTR + tid] = (_Float16)0.f;
    } else if (tid == ESTR) {
        const float c = 6.437751649736401f;      // 2*ln(25)
        inv_std[g] = rsqrtf(expm1f(c * tv) / c);
    }
}

// ---------------- kernel 2: main fused MLP, fully wave-private, ZERO barriers ----------------
// Per-wave 8KB LDS region (32 rows of this wave's nodes):
//   A0: rows [32][128] f16, stride 256B, swz ^((j&7)<<4)
//   A1 (reuse bytes [0,4096)):  [32][64] f16, stride 128B, swz ^((j&7)<<4)
//   A2 (bytes [4096,6144)):     [32][32] f16, stride  64B, swz ^((j&3)<<4)
// istd[128] floats at 32768. Total LDS 33280 B -> 4 blocks/CU, 16 waves/CU.

__device__ __forceinline__ float swishf(float x) {
    float e = __builtin_amdgcn_exp2f(x * -1.4426950408889634f);
    return x * __builtin_amdgcn_rcpf(1.0f + e);
}

__global__ __launch_bounds__(256, 4)
void scorenet_main(const float* __restrict__ node_attr,
                   const int* __restrict__ gptr, int B,
                   const _Float16* __restrict__ embedh,
                   const float* __restrict__ inv_std_g,
                   const _Float16* __restrict__ w0h,
                   const _Float16* __restrict__ w1h,
                   const _Float16* __restrict__ w2h,
                   const float* __restrict__ b0,
                   const float* __restrict__ b1,
                   const float* __restrict__ b2,
                   float* __restrict__ out) {
    __shared__ __align__(16) char lds[33280];

    const int t    = threadIdx.x;
    const int lane = t & 63;
    const int wid  = t >> 6;
    const int lr   = lane & 15;
    const int lk   = lane >> 4;
    const int wbase = blockIdx.x * MT + wid * WN;   // wave's first node

    char*  const a0    = lds + wid * 8192;
    float* const istdw = (float*)(lds + ISTD_OFF) + wid * WN;

    // ---- (1) issue independent node_attr loads first (hide under the search chain) ----
    const float4* asrc = (const float4*)(node_attr + (size_t)wbase * FEAT);
    float4 av[6];
    #pragma unroll
    for (int i = 0; i < 6; ++i) {
        int f4 = i * 64 + lane;
        if (f4 < 352) av[i] = asrc[f4];      // 32 rows x 11 float4
    }

    // ---- (2) seg lookup + embed gather (2 lanes per row) ----
    {
        int row  = lane >> 1;
        int node = wbase + row;
        int lo = 0, hi = B + 1;
        while (lo < hi) { int mid = (lo + hi) >> 1; if (gptr[mid] <= node) lo = mid + 1; else hi = mid; }
        int seg = lo - 1;
        if (!(lane & 1)) istdw[row] = inv_std_g[seg];
        const uint2* src = (const uint2*)(embedh + (size_t)seg * ESTR);
        int rot = row - (row >= 21 ? 21 : 0);          // row % 21
        const int rswz  = (row & 7) << 4;
        const int rbyte = row * 256;
        #pragma unroll
        for (int k = 0; k < 11; ++k) {
            int m = 2 * k + (lane & 1);
            if (m < 21) {
                int mm = m + rot; if (mm >= 21) mm -= 21;
                uint2 v = src[mm];
                int addr = rbyte + 88 + mm * 8;
                *(uint2*)(a0 + (addr ^ rswz)) = v;
            }
        }
    }

    // ---- (3) write node_attr to LDS (f16) ----
    #pragma unroll
    for (int i = 0; i < 6; ++i) {
        int f4 = i * 64 + lane;
        if (f4 < 352) {
            int row  = (int)(((unsigned)f4 * 381301u) >> 22);  // f4 / 11
            int colq = f4 - row * 11;
            union { _Float16 h[4]; uint2 u; } cv;
            cv.h[0] = (_Float16)av[i].x; cv.h[1] = (_Float16)av[i].y;
            cv.h[2] = (_Float16)av[i].z; cv.h[3] = (_Float16)av[i].w;
            int addr = row * 256 + colq * 8;
            *(uint2*)(a0 + (addr ^ ((row & 7) << 4))) = cv.u;
        }
    }

    // ---- weight/bias fragments (L1/L2-resident) ----
    f16x8 aw0[4][4];                       // [kt][mt] : A row = out-feature mt*16+lr
    #pragma unroll
    for (int kt = 0; kt < 4; ++kt)
        #pragma unroll
        for (int mt = 0; mt < 4; ++mt)
            aw0[kt][mt] = *(const f16x8*)(w0h + (mt * 16 + lr) * 128 + kt * 32 + lk * 8);
    f16x8 aw1[2][2];
    #pragma unroll
    for (int kt = 0; kt < 2; ++kt)
        #pragma unroll
        for (int mt = 0; mt < 2; ++mt)
            aw1[kt][mt] = *(const f16x8*)(w1h + (mt * 16 + lr) * 64 + kt * 32 + lk * 8);
    f16x8 aw2 = *(const f16x8*)(w2h + lr * 32 + lk * 8);
    float4 bias0[4];
    #pragma unroll
    for (int mt = 0; mt < 4; ++mt) bias0[mt] = *(const float4*)(b0 + mt * 16 + lk * 4);
    float4 bias1[2];
    #pragma unroll
    for (int mt = 0; mt < 2; ++mt) bias1[mt] = *(const float4*)(b1 + mt * 16 + lk * 4);
    float4 b2v = *(const float4*)b2;

    // NO __syncthreads anywhere: all LDS traffic below is wave-private,
    // same-wave DS ops are ordered by the compiler's lgkmcnt waits.

    // ---- layer 0: D^T[64 out][32 nodes] = W0 x X^T ----
    f32x4 acc0[4][2] = {};                 // [mt][nt]
    #pragma unroll
    for (int kt = 0; kt < 4; ++kt) {
        f16x8 bx[2];
        #pragma unroll
        for (int nt = 0; nt < 2; ++nt) {
            int j    = nt * 16 + lr;
            int addr = j * 256 + kt * 64 + lk * 16;
            bx[nt] = *(const f16x8*)(a0 + (addr ^ ((j & 7) << 4)));
        }
        #pragma unroll
        for (int mt = 0; mt < 4; ++mt)
            #pragma unroll
            for (int nt = 0; nt < 2; ++nt)
                acc0[mt][nt] = __builtin_amdgcn_mfma_f32_16x16x32_f16(aw0[kt][mt], bx[nt], acc0[mt][nt], 0, 0, 0);
    }
    // epilogue 0 -> A1 (lane holds 4 consecutive out-feats of node j)
    #pragma unroll
    for (int mt = 0; mt < 4; ++mt)
        #pragma unroll
        for (int nt = 0; nt < 2; ++nt) {
            int j = nt * 16 + lr;
            union { _Float16 h[4]; uint2 u; } p;
            p.h[0] = (_Float16)swishf(acc0[mt][nt][0] + bias0[mt].x);
            p.h[1] = (_Float16)swishf(acc0[mt][nt][1] + bias0[mt].y);
            p.h[2] = (_Float16)swishf(acc0[mt][nt][2] + bias0[mt].z);
            p.h[3] = (_Float16)swishf(acc0[mt][nt][3] + bias0[mt].w);
            int addr = j * 128 + (mt * 16 + lk * 4) * 2;
            *(uint2*)(a0 + (addr ^ ((j & 7) << 4))) = p.u;
        }

    // ---- layer 1: D^T[32 out][32 nodes] ----
    f32x4 acc1[2][2] = {};
    #pragma unroll
    for (int kt = 0; kt < 2; ++kt) {
        f16x8 bx[2];
        #pragma unroll
        for (int nt = 0; nt < 2; ++nt) {
            int j    = nt * 16 + lr;
            int addr = j * 128 + kt * 64 + lk * 16;
            bx[nt] = *(const f16x8*)(a0 + (addr ^ ((j & 7) << 4)));
        }
        #pragma unroll
        for (int mt = 0; mt < 2; ++mt)
            #pragma unroll
            for (int nt = 0; nt < 2; ++nt)
                acc1[mt][nt] = __builtin_amdgcn_mfma_f32_16x16x32_f16(aw1[kt][mt], bx[nt], acc1[mt][nt], 0, 0, 0);
    }
    // epilogue 1 -> A2 at +4096, stride 64B
    #pragma unroll
    for (int mt = 0; mt < 2; ++mt)
        #pragma unroll
        for (int nt = 0; nt < 2; ++nt) {
            int j = nt * 16 + lr;
            union { _Float16 h[4]; uint2 u; } p;
            p.h[0] = (_Float16)swishf(acc1[mt][nt][0] + bias1[mt].x);
            p.h[1] = (_Float16)swishf(acc1[mt][nt][1] + bias1[mt].y);
            p.h[2] = (_Float16)swishf(acc1[mt][nt][2] + bias1[mt].z);
            p.h[3] = (_Float16)swishf(acc1[mt][nt][3] + bias1[mt].w);
            int addr = 4096 + j * 64 + (mt * 16 + lk * 4) * 2;
            *(uint2*)(a0 + (addr ^ ((j & 3) << 4))) = p.u;
        }

    // ---- layer 2 + direct global store ----
    f32x4 acc2[2] = {};
    #pragma unroll
    for (int nt = 0; nt < 2; ++nt) {
        int j    = nt * 16 + lr;
        int addr = 4096 + j * 64 + lk * 16;
        f16x8 bx = *(const f16x8*)(a0 + (addr ^ ((j & 3) << 4)));
        acc2[nt] = __builtin_amdgcn_mfma_f32_16x16x32_f16(aw2, bx, acc2[nt], 0, 0, 0);
    }
    if (lk == 0) {
        #pragma unroll
        for (int nt = 0; nt < 2; ++nt) {
            int j = nt * 16 + lr;
            float is = istdw[j];
            float4 o;
            o.x = swishf(acc2[nt][0] + b2v.x) * is;
            o.y = swishf(acc2[nt][1] + b2v.y) * is;
            o.z = swishf(acc2[nt][2] + b2v.z) * is;
            o.w = swishf(acc2[nt][3] + b2v.w) * is;
            *(float4*)(out + (size_t)(wbase + j) * 4) = o;
        }
    }
}

// ---------------- launch ----------------
extern "C" void kernel_launch(void* const* d_in, const int* in_sizes, int n_in,
                              void* d_out, int out_size, void* d_ws, size_t ws_size,
                              hipStream_t stream) {
    const float* node_attr = (const float*)d_in[0];
    const float* t_arr     = (const float*)d_in[1];
    const int*   gptr      = (const int*)d_in[2];
    const float* W_f       = (const float*)d_in[3];
    const float* embed_w   = (const float*)d_in[4];
    const float* embed_b   = (const float*)d_in[5];
    const float* w0        = (const float*)d_in[6];
    const float* b0        = (const float*)d_in[7];
    const float* w1        = (const float*)d_in[8];
    const float* b1        = (const float*)d_in[9];
    const float* w2        = (const float*)d_in[10];
    const float* b2        = (const float*)d_in[11];
    float* out = (float*)d_out;

    const int N = in_sizes[0] / FEAT;
    const int B = in_sizes[1];

    char* ws = (char*)d_ws;
    size_t off = 0;
    _Float16* embedh = (_Float16*)(ws + off); off += (size_t)B * ESTR * sizeof(_Float16);
    off = (off + 1023) & ~(size_t)1023;
    float*    inv_std = (float*)(ws + off);   off += (size_t)B * sizeof(float);
    off = (off + 1023) & ~(size_t)1023;
    _Float16* w0h = (_Float16*)(ws + off);    off += 64 * 128 * sizeof(_Float16);
    _Float16* w1h = (_Float16*)(ws + off);    off += 32 * 64 * sizeof(_Float16);
    _Float16* w2h = (_Float16*)(ws + off);    off += 16 * 32 * sizeof(_Float16);

    embed_prep<<<B + 1, 128, 0, stream>>>(t_arr, W_f, embed_w, embed_b, w0, w1, w2,
                                          embedh, inv_std, w0h, w1h, w2h, B);
    scorenet_main<<<N / MT, 256, 0, stream>>>(node_attr, gptr, B, embedh, inv_std,
                                              w0h, w1h, w2h, b0, b1, b2, out);
}

// Round 5
// 104.285 us; speedup vs baseline: 1.3389x; 1.3389x over previous
//
#include <hip/hip_runtime.h>
#include <hip/hip_fp16.h>

typedef _Float16 f16x8 __attribute__((ext_vector_type(8)));
typedef __fp16   fp16x2 __attribute__((ext_vector_type(2)));   // cvt_pkrtz return type
typedef float f32x4 __attribute__((ext_vector_type(4)));

#define FEAT 44
#define TED  84
#define MT   128     // nodes per block
#define WN   32      // nodes per wave

// ---------------- kernel 0: per-node graph id (expand ptr) ----------------
__global__ void seg_prep(const int* __restrict__ gptr, int* __restrict__ seg) {
    int g = blockIdx.x;
    int a = gptr[g], b = gptr[g + 1];
    for (int i = a + threadIdx.x; i < b; i += 256) seg[i] = g;
}

// ---------------- kernel 1: per-graph emb0 = swish(embed) @ w0[:,44:]^T + b0 ; inv_std; weights ----------------
__global__ void embed_prep(const float* __restrict__ t_arr, const float* __restrict__ W_f,
                           const float* __restrict__ embed_w, const float* __restrict__ embed_b,
                           const float* __restrict__ w0, const float* __restrict__ b0,
                           const float* __restrict__ w1, const float* __restrict__ w2,
                           float* __restrict__ emb0, float* __restrict__ inv_std,
                           _Float16* __restrict__ w0h, _Float16* __restrict__ w1h,
                           _Float16* __restrict__ w2h, int B) {
    int g   = blockIdx.x;
    int tid = threadIdx.x;
    if (g == B) {   // weight repack block: w0h = [64 out][64 in] (cols 44..63 zero)
        for (int i = tid; i < 64 * 64; i += 128) {
            int o = i >> 6, k = i & 63;
            w0h[i] = (k < FEAT) ? (_Float16)w0[o * 128 + k] : (_Float16)0.f;
        }
        for (int i = tid; i < 32 * 64; i += 128) w1h[i] = (_Float16)w1[i];
        for (int i = tid; i < 16 * 32; i += 128) w2h[i] = (i < 4 * 32) ? (_Float16)w2[i] : (_Float16)0.f;
        return;
    }
    __shared__ float temb[TED];
    __shared__ float ses[TED];
    float tv = t_arr[g];
    if (tid < TED) {
        int j   = (tid < TED / 2) ? tid : tid - TED / 2;
        float x = tv * W_f[j] * 6.283185307179586f;
        temb[tid] = (tid < TED / 2) ? sinf(x) : cosf(x);
    }
    __syncthreads();
    if (tid < TED) {
        const float* wr = embed_w + tid * TED;
        float s = embed_b[tid];
        #pragma unroll 4
        for (int j = 0; j < TED; ++j) s = fmaf(temb[j], wr[j], s);
        ses[tid] = s / (1.0f + __expf(-s));
    }
    if (tid == TED) {
        const float c = 6.437751649736401f;      // 2*ln(25)
        inv_std[g] = rsqrtf(expm1f(c * tv) / c);
    }
    __syncthreads();
    if (tid < 64) {
        const float* wr = w0 + tid * 128 + FEAT;   // w0[tid][44..127]
        float s = b0[tid];
        #pragma unroll 4
        for (int j = 0; j < TED; ++j) s = fmaf(ses[j], wr[j], s);
        emb0[g * 64 + tid] = s;
    }
}

// ---------------- kernel 2: main fused MLP ----------------
// Per-wave 8KB LDS:
//   A0/A1 (reuse): [32][64] f16, row stride 128B, swz ^((j&7)<<4)
//   A2 at +4096:   [32][32] f16 in 128B rows (64B used), same swizzle
// 4 waves x 8KB = 32KB/block -> 4 blocks/CU at VGPR<=128 (waves_per_eu(4,4)).

__device__ __forceinline__ float swishf(float x) {
    float e = __builtin_amdgcn_exp2f(x * -1.4426950408889634f);
    return x * __builtin_amdgcn_rcpf(1.0f + e);
}

__device__ __forceinline__ int ubound(const int* __restrict__ p, int n, int v) {
    int lo = 0, hi = n;
    while (lo < hi) { int m = (lo + hi) >> 1; if (p[m] <= v) lo = m + 1; else hi = m; }
    return lo - 1;
}

template<bool USE_SEG>
__global__ __launch_bounds__(256) __attribute__((amdgpu_waves_per_eu(4, 4)))
void scorenet_main(const float* __restrict__ node_attr,
                   const int* __restrict__ gptr, int B,
                   const int* __restrict__ seg_arr,
                   const float* __restrict__ emb0,
                   const float* __restrict__ inv_std_g,
                   const _Float16* __restrict__ w0h,
                   const _Float16* __restrict__ w1h,
                   const _Float16* __restrict__ w2h,
                   const float* __restrict__ b1,
                   const float* __restrict__ b2,
                   float* __restrict__ out) {
    __shared__ __align__(16) char lds[32768];

    const int t    = threadIdx.x;
    const int lane = t & 63;
    const int wid  = t >> 6;
    const int lr   = lane & 15;
    const int lk   = lane >> 4;
    const int wbase = blockIdx.x * MT + wid * WN;

    char* const a0 = lds + wid * 8192;

    // ---- seg for this lane's two epilogue nodes (heads the longest chain) ----
    int seg0, seg1;
    if (USE_SEG) {
        seg0 = seg_arr[wbase + lr];
        seg1 = seg_arr[wbase + 16 + lr];
    } else {
        seg0 = ubound(gptr, B + 1, wbase + lr);
        seg1 = ubound(gptr, B + 1, wbase + 16 + lr);
    }

    // ---- independent node_attr loads ----
    const float4* asrc = (const float4*)(node_attr + (size_t)wbase * FEAT);
    float4 av[6];
    #pragma unroll
    for (int i = 0; i < 6; ++i) {
        int f4 = i * 64 + lane;
        if (f4 < 352) av[i] = asrc[f4];      // 32 rows x 11 float4
    }

    // ---- per-node layer-0 bias (emb0 gather) + inv_std ----
    float is0 = inv_std_g[seg0];
    float is1 = inv_std_g[seg1];
    f32x4 e0[4], e1[4];
    #pragma unroll
    for (int mt = 0; mt < 4; ++mt) {
        e0[mt] = *(const f32x4*)(emb0 + seg0 * 64 + mt * 16 + lk * 4);
        e1[mt] = *(const f32x4*)(emb0 + seg1 * 64 + mt * 16 + lk * 4);
    }

    // ---- stage node_attr -> LDS f16 (pkrtz), zero-fill cols 44..63 ----
    #pragma unroll
    for (int i = 0; i < 3; ++i) {            // 32 rows x 5 uint2 of zeros
        int k = i * 64 + lane;
        if (k < 160) {
            int row = (int)(((unsigned)k * 52429u) >> 18);   // k / 5
            int col = k - row * 5;
            int addr = row * 128 + 88 + col * 8;
            *(uint2*)(a0 + (addr ^ ((row & 7) << 4))) = make_uint2(0u, 0u);
        }
    }
    #pragma unroll
    for (int i = 0; i < 6; ++i) {
        int f4 = i * 64 + lane;
        if (f4 < 352) {
            int row  = (int)(((unsigned)f4 * 381301u) >> 22); // f4 / 11
            int colq = f4 - row * 11;
            union { fp16x2 h2[2]; uint2 u; } cv;
            cv.h2[0] = __builtin_amdgcn_cvt_pkrtz(av[i].x, av[i].y);
            cv.h2[1] = __builtin_amdgcn_cvt_pkrtz(av[i].z, av[i].w);
            int addr = row * 128 + colq * 8;
            *(uint2*)(a0 + (addr ^ ((row & 7) << 4))) = cv.u;
        }
    }

    // ---- weight / bias fragments ----
    f16x8 aw0[2][4];                          // [kt][mt], A row = out-feat mt*16+lr
    #pragma unroll
    for (int kt = 0; kt < 2; ++kt)
        #pragma unroll
        for (int mt = 0; mt < 4; ++mt)
            aw0[kt][mt] = *(const f16x8*)(w0h + (mt * 16 + lr) * 64 + kt * 32 + lk * 8);

    // ---- layer 0: D^T[64 out][32 nodes], K=64 ----
    f32x4 acc0[4][2] = {};
    #pragma unroll
    for (int kt = 0; kt < 2; ++kt) {
        f16x8 bx[2];
        #pragma unroll
        for (int nt = 0; nt < 2; ++nt) {
            int j    = nt * 16 + lr;
            int addr = j * 128 + kt * 64 + lk * 16;
            bx[nt] = *(const f16x8*)(a0 + (addr ^ ((j & 7) << 4)));
        }
        #pragma unroll
        for (int mt = 0; mt < 4; ++mt)
            #pragma unroll
            for (int nt = 0; nt < 2; ++nt)
                acc0[mt][nt] = __builtin_amdgcn_mfma_f32_16x16x32_f16(aw0[kt][mt], bx[nt], acc0[mt][nt], 0, 0, 0);
    }
    // epilogue 0 -> A1 (same region; per-wave DS ops are in-order)
    #pragma unroll
    for (int mt = 0; mt < 4; ++mt)
        #pragma unroll
        for (int nt = 0; nt < 2; ++nt) {
            int j = nt * 16 + lr;
            f32x4 e = nt ? e1[mt] : e0[mt];
            union { fp16x2 h2[2]; uint2 u; } p;
            p.h2[0] = __builtin_amdgcn_cvt_pkrtz(swishf(acc0[mt][nt][0] + e[0]),
                                                 swishf(acc0[mt][nt][1] + e[1]));
            p.h2[1] = __builtin_amdgcn_cvt_pkrtz(swishf(acc0[mt][nt][2] + e[2]),
                                                 swishf(acc0[mt][nt][3] + e[3]));
            int addr = j * 128 + (mt * 16 + lk * 4) * 2;
            *(uint2*)(a0 + (addr ^ ((j & 7) << 4))) = p.u;
        }

    f16x8 aw1[2][2];
    #pragma unroll
    for (int kt = 0; kt < 2; ++kt)
        #pragma unroll
        for (int mt = 0; mt < 2; ++mt)
            aw1[kt][mt] = *(const f16x8*)(w1h + (mt * 16 + lr) * 64 + kt * 32 + lk * 8);
    float4 bias1[2];
    #pragma unroll
    for (int mt = 0; mt < 2; ++mt) bias1[mt] = *(const float4*)(b1 + mt * 16 + lk * 4);

    // ---- layer 1: D^T[32 out][32 nodes], K=64 ----
    f32x4 acc1[2][2] = {};
    #pragma unroll
    for (int kt = 0; kt < 2; ++kt) {
        f16x8 bx[2];
        #pragma unroll
        for (int nt = 0; nt < 2; ++nt) {
            int j    = nt * 16 + lr;
            int addr = j * 128 + kt * 64 + lk * 16;
            bx[nt] = *(const f16x8*)(a0 + (addr ^ ((j & 7) << 4)));
        }
        #pragma unroll
        for (int mt = 0; mt < 2; ++mt)
            #pragma unroll
            for (int nt = 0; nt < 2; ++nt)
                acc1[mt][nt] = __builtin_amdgcn_mfma_f32_16x16x32_f16(aw1[kt][mt], bx[nt], acc1[mt][nt], 0, 0, 0);
    }
    // epilogue 1 -> A2 (+4096, 128B rows)
    #pragma unroll
    for (int mt = 0; mt < 2; ++mt)
        #pragma unroll
        for (int nt = 0; nt < 2; ++nt) {
            int j = nt * 16 + lr;
            union { fp16x2 h2[2]; uint2 u; } p;
            p.h2[0] = __builtin_amdgcn_cvt_pkrtz(swishf(acc1[mt][nt][0] + bias1[mt].x),
                                                 swishf(acc1[mt][nt][1] + bias1[mt].y));
            p.h2[1] = __builtin_amdgcn_cvt_pkrtz(swishf(acc1[mt][nt][2] + bias1[mt].z),
                                                 swishf(acc1[mt][nt][3] + bias1[mt].w));
            int addr = 4096 + j * 128 + (mt * 16 + lk * 4) * 2;
            *(uint2*)(a0 + (addr ^ ((j & 7) << 4))) = p.u;
        }

    f16x8 aw2 = *(const f16x8*)(w2h + lr * 32 + lk * 8);
    float4 b2v = *(const float4*)b2;

    // ---- layer 2 + direct global store ----
    f32x4 acc2[2] = {};
    #pragma unroll
    for (int nt = 0; nt < 2; ++nt) {
        int j    = nt * 16 + lr;
        int addr = 4096 + j * 128 + lk * 16;
        f16x8 bx = *(const f16x8*)(a0 + (addr ^ ((j & 7) << 4)));
        acc2[nt] = __builtin_amdgcn_mfma_f32_16x16x32_f16(aw2, bx, acc2[nt], 0, 0, 0);
    }
    if (lk == 0) {
        #pragma unroll
        for (int nt = 0; nt < 2; ++nt) {
            int j = nt * 16 + lr;
            float is = nt ? is1 : is0;
            float4 o;
            o.x = swishf(acc2[nt][0] + b2v.x) * is;
            o.y = swishf(acc2[nt][1] + b2v.y) * is;
            o.z = swishf(acc2[nt][2] + b2v.z) * is;
            o.w = swishf(acc2[nt][3] + b2v.w) * is;
            *(float4*)(out + (size_t)(wbase + j) * 4) = o;
        }
    }
}

// ---------------- launch ----------------
extern "C" void kernel_launch(void* const* d_in, const int* in_sizes, int n_in,
                              void* d_out, int out_size, void* d_ws, size_t ws_size,
                              hipStream_t stream) {
    const float* node_attr = (const float*)d_in[0];
    const float* t_arr     = (const float*)d_in[1];
    const int*   gptr      = (const int*)d_in[2];
    const float* W_f       = (const float*)d_in[3];
    const float* embed_w   = (const float*)d_in[4];
    const float* embed_b   = (const float*)d_in[5];
    const float* w0        = (const float*)d_in[6];
    const float* b0        = (const float*)d_in[7];
    const float* w1        = (const float*)d_in[8];
    const float* b1        = (const float*)d_in[9];
    const float* w2        = (const float*)d_in[10];
    const float* b2        = (const float*)d_in[11];
    float* out = (float*)d_out;

    const int N = in_sizes[0] / FEAT;
    const int B = in_sizes[2] - 1;

    char* ws = (char*)d_ws;
    size_t off = 0;
    float*    emb0    = (float*)(ws + off); off += (size_t)B * 64 * sizeof(float);
    off = (off + 1023) & ~(size_t)1023;
    float*    inv_std = (float*)(ws + off); off += (size_t)B * sizeof(float);
    off = (off + 1023) & ~(size_t)1023;
    _Float16* w0h = (_Float16*)(ws + off);  off += 64 * 64 * sizeof(_Float16);
    _Float16* w1h = (_Float16*)(ws + off);  off += 32 * 64 * sizeof(_Float16);
    _Float16* w2h = (_Float16*)(ws + off);  off += 16 * 32 * sizeof(_Float16);
    off = (off + 1023) & ~(size_t)1023;
    int* seg = (int*)(ws + off);
    size_t need_with_seg = off + (size_t)N * sizeof(int);
    bool use_seg = (ws_size >= need_with_seg);

    embed_prep<<<B + 1, 128, 0, stream>>>(t_arr, W_f, embed_w, embed_b, w0, b0, w1, w2,
                                          emb0, inv_std, w0h, w1h, w2h, B);
    if (use_seg) {
        seg_prep<<<B, 256, 0, stream>>>(gptr, seg);
        scorenet_main<true><<<N / MT, 256, 0, stream>>>(node_attr, gptr, B, seg, emb0, inv_std,
                                                        w0h, w1h, w2h, b1, b2, out);
    } else {
        scorenet_main<false><<<N / MT, 256, 0, stream>>>(node_attr, gptr, B, seg, emb0, inv_std,
                                                         w0h, w1h, w2h, b1, b2, out);
    }
}

// Round 6
// 103.637 us; speedup vs baseline: 1.3472x; 1.0062x over previous
//
#include <hip/hip_runtime.h>
#include <hip/hip_fp16.h>

typedef _Float16 f16x8 __attribute__((ext_vector_type(8)));
typedef __fp16   fp16x2 __attribute__((ext_vector_type(2)));   // cvt_pkrtz return type
typedef float f32x4 __attribute__((ext_vector_type(4)));

#define FEAT 44
#define TED  84
#define MT   128     // nodes per block
#define WN   32      // nodes per wave

// ---------------- kernel 0: per-node graph id (expand ptr) ----------------
__global__ void seg_prep(const int* __restrict__ gptr, int* __restrict__ seg) {
    int g = blockIdx.x;
    int a = gptr[g], b = gptr[g + 1];
    for (int i = a + threadIdx.x; i < b; i += 256) seg[i] = g;
}

// ---------------- kernel 1: per-graph emb0 = swish(embed) @ w0[:,44:]^T + b0 ; inv_std; weights ----------------
__global__ void embed_prep(const float* __restrict__ t_arr, const float* __restrict__ W_f,
                           const float* __restrict__ embed_w, const float* __restrict__ embed_b,
                           const float* __restrict__ w0, const float* __restrict__ b0,
                           const float* __restrict__ w1, const float* __restrict__ w2,
                           float* __restrict__ emb0, float* __restrict__ inv_std,
                           _Float16* __restrict__ w0h, _Float16* __restrict__ w1h,
                           _Float16* __restrict__ w2h, int B) {
    int g   = blockIdx.x;
    int tid = threadIdx.x;
    if (g == B) {   // weight repack block: w0h = [64 out][64 in] (cols 44..63 zero)
        for (int i = tid; i < 64 * 64; i += 128) {
            int o = i >> 6, k = i & 63;
            w0h[i] = (k < FEAT) ? (_Float16)w0[o * 128 + k] : (_Float16)0.f;
        }
        for (int i = tid; i < 32 * 64; i += 128) w1h[i] = (_Float16)w1[i];
        for (int i = tid; i < 16 * 32; i += 128) w2h[i] = (i < 4 * 32) ? (_Float16)w2[i] : (_Float16)0.f;
        return;
    }
    __shared__ float temb[TED];
    __shared__ float ses[TED];
    float tv = t_arr[g];
    if (tid < TED) {
        int j   = (tid < TED / 2) ? tid : tid - TED / 2;
        float x = tv * W_f[j] * 6.283185307179586f;
        temb[tid] = (tid < TED / 2) ? sinf(x) : cosf(x);
    }
    __syncthreads();
    if (tid < TED) {
        const float* wr = embed_w + tid * TED;
        float s = embed_b[tid];
        #pragma unroll 4
        for (int j = 0; j < TED; ++j) s = fmaf(temb[j], wr[j], s);
        ses[tid] = s / (1.0f + __expf(-s));
    }
    if (tid == TED) {
        const float c = 6.437751649736401f;      // 2*ln(25)
        inv_std[g] = rsqrtf(expm1f(c * tv) / c);
    }
    __syncthreads();
    if (tid < 64) {
        const float* wr = w0 + tid * 128 + FEAT;   // w0[tid][44..127]
        float s = b0[tid];
        #pragma unroll 4
        for (int j = 0; j < TED; ++j) s = fmaf(ses[j], wr[j], s);
        emb0[g * 64 + tid] = s;
    }
}

// ---------------- kernel 2: main fused MLP ----------------
// Per-wave 8KB LDS:
//   A0/A1 (reuse): [32][64] f16, row stride 128B, swz ^((j&7)<<4)
//   A2 at +4096:   [32][32] f16 in 128B rows (64B used), same swizzle
// All additive terms (emb0, b1, b2) are folded into the MFMA C-operand init,
// keeping peak live VGPRs ~<100 so waves_per_eu(4,4) holds WITHOUT spills.

__device__ __forceinline__ float swishf(float x) {
    float e = __builtin_amdgcn_exp2f(x * -1.4426950408889634f);
    return x * __builtin_amdgcn_rcpf(1.0f + e);
}

__device__ __forceinline__ int ubound(const int* __restrict__ p, int n, int v) {
    int lo = 0, hi = n;
    while (lo < hi) { int m = (lo + hi) >> 1; if (p[m] <= v) lo = m + 1; else hi = m; }
    return lo - 1;
}

template<bool USE_SEG>
__global__ __launch_bounds__(256) __attribute__((amdgpu_waves_per_eu(4, 4)))
void scorenet_main(const float* __restrict__ node_attr,
                   const int* __restrict__ gptr, int B,
                   const int* __restrict__ seg_arr,
                   const float* __restrict__ emb0,
                   const float* __restrict__ inv_std_g,
                   const _Float16* __restrict__ w0h,
                   const _Float16* __restrict__ w1h,
                   const _Float16* __restrict__ w2h,
                   const float* __restrict__ b1,
                   const float* __restrict__ b2,
                   float* __restrict__ out) {
    __shared__ __align__(16) char lds[32768];

    const int t    = threadIdx.x;
    const int lane = t & 63;
    const int wid  = t >> 6;
    const int lr   = lane & 15;
    const int lk   = lane >> 4;
    const int wbase = blockIdx.x * MT + wid * WN;

    char* const a0 = lds + wid * 8192;

    // ---- seg for this lane's two epilogue nodes (heads the longest chain) ----
    int seg0, seg1;
    if (USE_SEG) {
        seg0 = seg_arr[wbase + lr];
        seg1 = seg_arr[wbase + 16 + lr];
    } else {
        seg0 = ubound(gptr, B + 1, wbase + lr);
        seg1 = ubound(gptr, B + 1, wbase + 16 + lr);
    }

    // ---- independent node_attr loads ----
    const float4* asrc = (const float4*)(node_attr + (size_t)wbase * FEAT);
    float4 av[6];
    #pragma unroll
    for (int i = 0; i < 6; ++i) {
        int f4 = i * 64 + lane;
        if (f4 < 352) av[i] = asrc[f4];      // 32 rows x 11 float4
    }

    // ---- inv_std ----
    float is0 = inv_std_g[seg0];
    float is1 = inv_std_g[seg1];

    // ---- layer-0 accumulators init = per-node emb0 bias (C-operand fold) ----
    // acc0[mt][nt][r] <-> out-feat o = mt*16 + lk*4 + r of node j = nt*16 + lr
    f32x4 acc0[4][2];
    #pragma unroll
    for (int mt = 0; mt < 4; ++mt) {
        acc0[mt][0] = *(const f32x4*)(emb0 + seg0 * 64 + mt * 16 + lk * 4);
        acc0[mt][1] = *(const f32x4*)(emb0 + seg1 * 64 + mt * 16 + lk * 4);
    }

    // ---- stage node_attr -> LDS f16 (pkrtz), zero-fill cols 44..63 ----
    #pragma unroll
    for (int i = 0; i < 3; ++i) {            // 32 rows x 5 uint2 of zeros
        int k = i * 64 + lane;
        if (k < 160) {
            int row = (int)(((unsigned)k * 52429u) >> 18);   // k / 5
            int col = k - row * 5;
            int addr = row * 128 + 88 + col * 8;
            *(uint2*)(a0 + (addr ^ ((row & 7) << 4))) = make_uint2(0u, 0u);
        }
    }
    #pragma unroll
    for (int i = 0; i < 6; ++i) {
        int f4 = i * 64 + lane;
        if (f4 < 352) {
            int row  = (int)(((unsigned)f4 * 381301u) >> 22); // f4 / 11
            int colq = f4 - row * 11;
            union { fp16x2 h2[2]; uint2 u; } cv;
            cv.h2[0] = __builtin_amdgcn_cvt_pkrtz(av[i].x, av[i].y);
            cv.h2[1] = __builtin_amdgcn_cvt_pkrtz(av[i].z, av[i].w);
            int addr = row * 128 + colq * 8;
            *(uint2*)(a0 + (addr ^ ((row & 7) << 4))) = cv.u;
        }
    }

    // ---- weight fragments for layer 0 ----
    f16x8 aw0[2][4];                          // [kt][mt], A row = out-feat mt*16+lr
    #pragma unroll
    for (int kt = 0; kt < 2; ++kt)
        #pragma unroll
        for (int mt = 0; mt < 4; ++mt)
            aw0[kt][mt] = *(const f16x8*)(w0h + (mt * 16 + lr) * 64 + kt * 32 + lk * 8);

    // ---- layer 0: D^T[64 out][32 nodes], K=64, C-init = emb0 ----
    #pragma unroll
    for (int kt = 0; kt < 2; ++kt) {
        f16x8 bx[2];
        #pragma unroll
        for (int nt = 0; nt < 2; ++nt) {
            int j    = nt * 16 + lr;
            int addr = j * 128 + kt * 64 + lk * 16;
            bx[nt] = *(const f16x8*)(a0 + (addr ^ ((j & 7) << 4)));
        }
        #pragma unroll
        for (int mt = 0; mt < 4; ++mt)
            #pragma unroll
            for (int nt = 0; nt < 2; ++nt)
                acc0[mt][nt] = __builtin_amdgcn_mfma_f32_16x16x32_f16(aw0[kt][mt], bx[nt], acc0[mt][nt], 0, 0, 0);
    }
    // epilogue 0 -> A1 (same region; per-wave DS ops are in-order)
    #pragma unroll
    for (int mt = 0; mt < 4; ++mt)
        #pragma unroll
        for (int nt = 0; nt < 2; ++nt) {
            int j = nt * 16 + lr;
            union { fp16x2 h2[2]; uint2 u; } p;
            p.h2[0] = __builtin_amdgcn_cvt_pkrtz(swishf(acc0[mt][nt][0]), swishf(acc0[mt][nt][1]));
            p.h2[1] = __builtin_amdgcn_cvt_pkrtz(swishf(acc0[mt][nt][2]), swishf(acc0[mt][nt][3]));
            int addr = j * 128 + (mt * 16 + lk * 4) * 2;
            *(uint2*)(a0 + (addr ^ ((j & 7) << 4))) = p.u;
        }

    // ---- layer-1 weights + C-init = b1 ----
    f16x8 aw1[2][2];
    #pragma unroll
    for (int kt = 0; kt < 2; ++kt)
        #pragma unroll
        for (int mt = 0; mt < 2; ++mt)
            aw1[kt][mt] = *(const f16x8*)(w1h + (mt * 16 + lr) * 64 + kt * 32 + lk * 8);
    f32x4 acc1[2][2];
    #pragma unroll
    for (int mt = 0; mt < 2; ++mt) {
        float4 bv = *(const float4*)(b1 + mt * 16 + lk * 4);
        acc1[mt][0] = f32x4{bv.x, bv.y, bv.z, bv.w};
        acc1[mt][1] = acc1[mt][0];
    }

    // ---- layer 1: D^T[32 out][32 nodes], K=64 ----
    #pragma unroll
    for (int kt = 0; kt < 2; ++kt) {
        f16x8 bx[2];
        #pragma unroll
        for (int nt = 0; nt < 2; ++nt) {
            int j    = nt * 16 + lr;
            int addr = j * 128 + kt * 64 + lk * 16;
            bx[nt] = *(const f16x8*)(a0 + (addr ^ ((j & 7) << 4)));
        }
        #pragma unroll
        for (int mt = 0; mt < 2; ++mt)
            #pragma unroll
            for (int nt = 0; nt < 2; ++nt)
                acc1[mt][nt] = __builtin_amdgcn_mfma_f32_16x16x32_f16(aw1[kt][mt], bx[nt], acc1[mt][nt], 0, 0, 0);
    }
    // epilogue 1 -> A2 (+4096, 128B rows)
    #pragma unroll
    for (int mt = 0; mt < 2; ++mt)
        #pragma unroll
        for (int nt = 0; nt < 2; ++nt) {
            int j = nt * 16 + lr;
            union { fp16x2 h2[2]; uint2 u; } p;
            p.h2[0] = __builtin_amdgcn_cvt_pkrtz(swishf(acc1[mt][nt][0]), swishf(acc1[mt][nt][1]));
            p.h2[1] = __builtin_amdgcn_cvt_pkrtz(swishf(acc1[mt][nt][2]), swishf(acc1[mt][nt][3]));
            int addr = 4096 + j * 128 + (mt * 16 + lk * 4) * 2;
            *(uint2*)(a0 + (addr ^ ((j & 7) << 4))) = p.u;
        }

    // ---- layer 2: C-init = b2 in the valid (lk==0) rows; w2 rows 4..15 are zero ----
    f16x8 aw2 = *(const f16x8*)(w2h + lr * 32 + lk * 8);
    float4 b2v = *(const float4*)b2;
    f32x4 c2init = (lk == 0) ? f32x4{b2v.x, b2v.y, b2v.z, b2v.w} : f32x4{0.f, 0.f, 0.f, 0.f};

    f32x4 acc2[2] = {c2init, c2init};
    #pragma unroll
    for (int nt = 0; nt < 2; ++nt) {
        int j    = nt * 16 + lr;
        int addr = 4096 + j * 128 + lk * 16;
        f16x8 bx = *(const f16x8*)(a0 + (addr ^ ((j & 7) << 4)));
        acc2[nt] = __builtin_amdgcn_mfma_f32_16x16x32_f16(aw2, bx, acc2[nt], 0, 0, 0);
    }
    if (lk == 0) {
        #pragma unroll
        for (int nt = 0; nt < 2; ++nt) {
            int j = nt * 16 + lr;
            float is = nt ? is1 : is0;
            float4 o;
            o.x = swishf(acc2[nt][0]) * is;
            o.y = swishf(acc2[nt][1]) * is;
            o.z = swishf(acc2[nt][2]) * is;
            o.w = swishf(acc2[nt][3]) * is;
            *(float4*)(out + (size_t)(wbase + j) * 4) = o;
        }
    }
}

// ---------------- launch ----------------
extern "C" void kernel_launch(void* const* d_in, const int* in_sizes, int n_in,
                              void* d_out, int out_size, void* d_ws, size_t ws_size,
                              hipStream_t stream) {
    const float* node_attr = (const float*)d_in[0];
    const float* t_arr     = (const float*)d_in[1];
    const int*   gptr      = (const int*)d_in[2];
    const float* W_f       = (const float*)d_in[3];
    const float* embed_w   = (const float*)d_in[4];
    const float* embed_b   = (const float*)d_in[5];
    const float* w0        = (const float*)d_in[6];
    const float* b0        = (const float*)d_in[7];
    const float* w1        = (const float*)d_in[8];
    const float* b1        = (const float*)d_in[9];
    const float* w2        = (const float*)d_in[10];
    const float* b2        = (const float*)d_in[11];
    float* out = (float*)d_out;

    const int N = in_sizes[0] / FEAT;
    const int B = in_sizes[2] - 1;

    char* ws = (char*)d_ws;
    size_t off = 0;
    float*    emb0    = (float*)(ws + off); off += (size_t)B * 64 * sizeof(float);
    off = (off + 1023) & ~(size_t)1023;
    float*    inv_std = (float*)(ws + off); off += (size_t)B * sizeof(float);
    off = (off + 1023) & ~(size_t)1023;
    _Float16* w0h = (_Float16*)(ws + off);  off += 64 * 64 * sizeof(_Float16);
    _Float16* w1h = (_Float16*)(ws + off);  off += 32 * 64 * sizeof(_Float16);
    _Float16* w2h = (_Float16*)(ws + off);  off += 16 * 32 * sizeof(_Float16);
    off = (off + 1023) & ~(size_t)1023;
    int* seg = (int*)(ws + off);
    size_t need_with_seg = off + (size_t)N * sizeof(int);
    bool use_seg = (ws_size >= need_with_seg);

    embed_prep<<<B + 1, 128, 0, stream>>>(t_arr, W_f, embed_w, embed_b, w0, b0, w1, w2,
                                          emb0, inv_std, w0h, w1h, w2h, B);
    if (use_seg) {
        seg_prep<<<B, 256, 0, stream>>>(gptr, seg);
        scorenet_main<true><<<N / MT, 256, 0, stream>>>(node_attr, gptr, B, seg, emb0, inv_std,
                                                        w0h, w1h, w2h, b1, b2, out);
    } else {
        scorenet_main<false><<<N / MT, 256, 0, stream>>>(node_attr, gptr, B, seg, emb0, inv_std,
                                                         w0h, w1h, w2h, b1, b2, out);
    }
}